// Round 2
// baseline (285.768 us; speedup 1.0000x reference)
//
#include <hip/hip_runtime.h>

#define HW 32768      // H*W per batch = 128*256
#define WIDTH 256

typedef float f32x4 __attribute__((ext_vector_type(4)));
typedef short s16x8 __attribute__((ext_vector_type(8)));

__device__ __forceinline__ unsigned short f2bf(float f){
    unsigned int u = __float_as_uint(f);
    u += 0x7FFFu + ((u >> 16) & 1u);      // round-to-nearest-even
    return (unsigned short)(u >> 16);
}
__device__ __forceinline__ unsigned int pk2(float a, float b){
    return (unsigned int)f2bf(a) | ((unsigned int)f2bf(b) << 16);
}

// ---------------------------------------------------------------------------
// k_pre: blocks 0..63 = W1/W2 pre-pack into bf16 MFMA A-fragment layout
//        block 64 = collapsed geo path (M = Wsel x Wgeo, c0 = collapsed bias)
// ---------------------------------------------------------------------------
__global__ void k_pre(const float* __restrict__ W1, const float* __restrict__ W2,
                      unsigned int* __restrict__ Wb,
                      const float* __restrict__ Wsel, const float* __restrict__ bsel,
                      const float* __restrict__ Wgeo, const float* __restrict__ bgeo,
                      float* __restrict__ M, float* __restrict__ c0)
{
    if (blockIdx.x < 64){
        const int pi = blockIdx.x * 256 + threadIdx.x;   // 0..16383
        const int j2   = pi & 3;
        const int l15  = (pi >> 2) & 15;
        const int quad = (pi >> 6) & 3;
        const int m    = (pi >> 8) & 7;
        const int kk   = (pi >> 11) & 3;
        const int F    = (pi >> 13) & 1;
        const float* Wm = F ? W2 : W1;
        const int row = m * 16 + l15;
        const int ch  = kk * 32 + quad * 8 + j2 * 2;
        Wb[pi] = pk2(Wm[row * 128 + ch], Wm[row * 128 + ch + 1]);
    } else {
        for (int u = threadIdx.x; u < 444; u += 256){
            if (u < 441){
                int s = u / 147; int r = u % 147; int i = r / 49; int k = r % 49;
                float acc = 0.f;
                for (int o = 0; o < 96; ++o)
                    acc += Wsel[s * 288 + i * 96 + o] * Wgeo[o * 49 + k];
                M[u] = acc;
            } else {
                int s = u - 441;
                float acc = bsel[s];
                for (int i = 0; i < 3; ++i)
                    for (int o = 0; o < 96; ++o)
                        acc += Wsel[s * 288 + i * 96 + o] * bgeo[o];
                c0[s] = acc;
            }
        }
    }
}

// ---------------------------------------------------------------------------
// Fused kernel, 512 threads (8 waves) per block, one (b,h) row per block.
// Same LDS row buffer as the 256-thr version -> 2 blocks/CU still fit, but
// 16 waves/CU instead of 8 (4/SIMD). Each wave owns 32 px (2 nt-tiles).
// Epilogue: thread-halves split the 49 dd planes; logit partials combined
// through LDS; softmax per-pixel; final written by both halves.
// ---------------------------------------------------------------------------
__global__ __launch_bounds__(512, 4) void k_fused(
    const float* __restrict__ fl, const float* __restrict__ fr,
    const unsigned int* __restrict__ Wbu,
    const float* __restrict__ b1, const float* __restrict__ b2,
    const float* __restrict__ cv0, const float* __restrict__ cv1,
    const float* __restrict__ cv2,
    const float* __restrict__ Mg, const float* __restrict__ c0g,
    float* __restrict__ icO, float* __restrict__ finalO, float* __restrict__ wO)
{
    __shared__ __align__(16) char pool[67584];      // f2s -> G (time-aliased)
    __shared__ float s1[256], s2[256];
    __shared__ float Ms[441];
    __shared__ float c0s[3];
    __shared__ float lgp[3][512];                   // logit partials -> w
    unsigned short* f2s = (unsigned short*)pool;    // [256 px][132] bf16
    float* G            = (float*)pool;             // [256 rows][66] f32

    const int blk  = blockIdx.x;          // 512 = 4 b x 128 h
    const int b    = blk >> 7;
    const int h    = blk & 127;
    const int tid  = threadIdx.x;
    const int wv   = tid >> 6;            // 0..7
    const int lane = tid & 63;
    const int quad = lane >> 4;
    const int l15  = lane & 15;

    for (int i = tid; i < 441; i += 512) Ms[i] = Mg[i];
    if (tid < 3) c0s[tid] = c0g[tid];

    const float* feats[2] = { fl + (size_t)b * 128 * HW + h * WIDTH,
                              fr + (size_t)b * 128 * HW + h * WIDTH };
    const float* bss[2]   = { b1, b2 };

    unsigned int f1p[32];                 // f1 raw bf16 pairs (wave's 32 px)

    #pragma unroll 1
    for (int Fi = 0; Fi < 2; ++Fi){
        const int F = 1 - Fi;             // f2 first, then f1
        const float* featB = feats[F];
        const float* bias  = bss[F];
        const unsigned int* WbF = Wbu + F * 8192;

        f32x4 acc[8][2];
        #pragma unroll
        for (int m = 0; m < 8; ++m)
            #pragma unroll
            for (int nt = 0; nt < 2; ++nt)
                acc[m][nt] = (f32x4){0.f, 0.f, 0.f, 0.f};

        float buf[3][8];
        // tile t = kk*2+nt ; px = wv*32 + nt*16 + l15 ; preload t = 0,1 (kk=0)
        #pragma unroll
        for (int t = 0; t < 2; ++t){
            const float* bp = featB + (size_t)(quad * 8) * HW + wv * 32 + t * 16 + l15;
            #pragma unroll
            for (int j = 0; j < 8; ++j) buf[t][j] = bp[(size_t)j * HW];
        }

        #pragma unroll
        for (int kk = 0; kk < 4; ++kk){
            union { unsigned int u[4]; s16x8 v; } rb[2];
            #pragma unroll
            for (int nt = 0; nt < 2; ++nt){
                const int t = kk * 2 + nt;
                if (t + 2 < 8){           // 2-deep pipeline
                    const int kk2 = (t + 2) >> 1, nt2 = (t + 2) & 1;
                    const float* bp = featB + (size_t)(kk2 * 32 + quad * 8) * HW
                                      + wv * 32 + nt2 * 16 + l15;
                    #pragma unroll
                    for (int j = 0; j < 8; ++j) buf[(t + 2) % 3][j] = bp[(size_t)j * HW];
                }
                const float* cur = buf[t % 3];
                rb[nt].u[0] = pk2(cur[0], cur[1]); rb[nt].u[1] = pk2(cur[2], cur[3]);
                rb[nt].u[2] = pk2(cur[4], cur[5]); rb[nt].u[3] = pk2(cur[6], cur[7]);
            }
            #pragma unroll
            for (int m = 0; m < 8; ++m){
                const s16x8 af = *(const s16x8*)&WbF[(((kk * 8 + m) * 4 + quad) * 16 + l15) * 4];
                acc[m][0] = __builtin_amdgcn_mfma_f32_16x16x32_bf16(af, rb[0].v, acc[m][0], 0, 0, 0);
                acc[m][1] = __builtin_amdgcn_mfma_f32_16x16x32_bf16(af, rb[1].v, acc[m][1], 0, 0, 0);
            }
        }

        // bias + inverse-norm per pixel
        float inv[2];
        #pragma unroll
        for (int nt = 0; nt < 2; ++nt){
            #pragma unroll
            for (int m = 0; m < 8; ++m)
                acc[m][nt] += *(const f32x4*)(bias + m * 16 + quad * 4);
            float n2 = 0.f;
            #pragma unroll
            for (int m = 0; m < 8; ++m)
                #pragma unroll
                for (int r = 0; r < 4; ++r)
                    n2 += acc[m][nt][r] * acc[m][nt][r];
            n2 += __shfl_xor(n2, 16, 64);
            n2 += __shfl_xor(n2, 32, 64);
            inv[nt] = 1.f / (sqrtf(n2) + 1e-8f);
        }

        if (F == 1){                      // f2 -> LDS (raw bf16) + s2
            if (quad == 0){
                #pragma unroll
                for (int nt = 0; nt < 2; ++nt) s2[wv * 32 + nt * 16 + l15] = inv[nt];
            }
            #pragma unroll
            for (int nt = 0; nt < 2; ++nt){
                const int px = wv * 32 + nt * 16 + l15;
                #pragma unroll
                for (int m = 0; m < 8; ++m){
                    uint2 p;
                    p.x = pk2(acc[m][nt][0], acc[m][nt][1]);
                    p.y = pk2(acc[m][nt][2], acc[m][nt][3]);
                    *(uint2*)&f2s[px * 132 + m * 16 + quad * 4] = p;
                }
            }
        } else {                          // f1 -> registers (raw bf16) + s1
            #pragma unroll
            for (int m = 0; m < 8; ++m)
                #pragma unroll
                for (int nt = 0; nt < 2; ++nt){
                    f1p[m * 4 + nt * 2 + 0] = pk2(acc[m][nt][0], acc[m][nt][1]);
                    f1p[m * 4 + nt * 2 + 1] = pk2(acc[m][nt][2], acc[m][nt][3]);
                }
            if (quad == 0){
                #pragma unroll
                for (int nt = 0; nt < 2; ++nt) s1[wv * 32 + nt * 16 + l15] = inv[nt];
            }
        }
    }
    __syncthreads();                      // f2s complete

    // ---- correlation: per wave 2 strips of 16 px; A from f1p shuffles ----
    f32x4 acc_c[2][4];
    #pragma unroll
    for (int st = 0; st < 2; ++st)
        #pragma unroll
        for (int ct = 0; ct < 4; ++ct)
            acc_c[st][ct] = (f32x4){0.f, 0.f, 0.f, 0.f};

    #pragma unroll
    for (int st = 0; st < 2; ++st){
        s16x8 afc[4];
        #pragma unroll
        for (int kk = 0; kk < 4; ++kk){
            union { unsigned int u[4]; s16x8 v; } r;
            #pragma unroll
            for (int j2 = 0; j2 < 4; ++j2){
                const int rp  = j2 & 1;
                const int qs  = (quad & 1) * 2 + (j2 >> 1);
                const int src = qs * 16 + l15;
                unsigned int a0 = (unsigned int)__shfl((int)f1p[(kk * 2 + 0) * 4 + st * 2 + rp], src, 64);
                unsigned int a1 = (unsigned int)__shfl((int)f1p[(kk * 2 + 1) * 4 + st * 2 + rp], src, 64);
                r.u[j2] = (quad >> 1) ? a1 : a0;
            }
            afc[kk] = r.v;
        }
        #pragma unroll
        for (int ct = 0; ct < 4; ++ct){
            const int s = wv * 32 + st * 16 + ct * 16 + l15 - 24;
            const bool valid = (s >= 0) && (s < WIDTH);
            const int sc = valid ? s : 0;
            #pragma unroll
            for (int kk = 0; kk < 4; ++kk){
                union { uint2 q2[2]; s16x8 v; } rb;
                rb.q2[0] = *(const uint2*)&f2s[sc * 132 + kk * 32 + quad * 8];
                rb.q2[1] = *(const uint2*)&f2s[sc * 132 + kk * 32 + quad * 8 + 4];
                s16x8 bf = rb.v;
                if (!valid) bf = (s16x8){0,0,0,0,0,0,0,0};
                acc_c[st][ct] = __builtin_amdgcn_mfma_f32_16x16x32_bf16(afc[kk], bf, acc_c[st][ct], 0, 0, 0);
            }
        }
    }
    __syncthreads();                      // all f2s reads done; G overwrites pool
    #pragma unroll
    for (int st = 0; st < 2; ++st)
        #pragma unroll
        for (int ct = 0; ct < 4; ++ct)
            #pragma unroll
            for (int r = 0; r < 4; ++r)
                G[((wv * 2 + st) * 16 + quad * 4 + r) * 66 + ct * 16 + l15] = acc_c[st][ct][r];
    __syncthreads();

    // ---- fused epilogue: px = tid&255; thread-halves split the dd planes ----
    // out[dd][px] = G[px][(px&15)+48-dd] * s1[px] * s2[px+24-dd]  (G=0 when OOB)
    const int px   = tid & 255;
    const int half = tid >> 8;
    const float sc1 = s1[px];
    const float* Gp = &G[px * 66 + (px & 15) + 48];
    const size_t rowoff = (size_t)h * WIDTH + px;
    const size_t cvbase = (size_t)b * 49 * HW + rowoff;
    float* icb = icO    + cvbase;
    float* fnb = finalO + cvbase;
    const float* c0p = cv0 + cvbase;
    const float* c1p = cv1 + cvbase;
    const float* c2p = cv2 + cvbase;

    const int dd0 = half * 25;            // half0: dd 0..24, half1: dd 25..48

    float lg0 = 0.f, lg1 = 0.f, lg2 = 0.f;
    #pragma unroll 5
    for (int i = 0; i < 25; ++i){
        const int dd = dd0 + i;
        if (dd < 49){
            int s2i = px + 24 - dd;
            s2i = s2i < 0 ? 0 : (s2i > 255 ? 255 : s2i);   // OOB -> G row is 0 anyway
            const float icv = Gp[-dd] * sc1 * s2[s2i];
            icb[(size_t)dd * HW] = icv;
            const float a0 = c0p[(size_t)dd * HW];
            const float a1 = c1p[(size_t)dd * HW];
            const float a2 = c2p[(size_t)dd * HW];
            lg0 += Ms[dd]       * a0 + Ms[49  + dd] * a1 + Ms[98  + dd] * a2;
            lg1 += Ms[147 + dd] * a0 + Ms[196 + dd] * a1 + Ms[245 + dd] * a2;
            lg2 += Ms[294 + dd] * a0 + Ms[343 + dd] * a1 + Ms[392 + dd] * a2;
        }
    }
    lgp[0][tid] = lg0; lgp[1][tid] = lg1; lgp[2][tid] = lg2;
    __syncthreads();

    if (tid < 256){
        const float L0 = c0s[0] + lgp[0][tid] + lgp[0][tid + 256];
        const float L1 = c0s[1] + lgp[1][tid] + lgp[1][tid + 256];
        const float L2 = c0s[2] + lgp[2][tid] + lgp[2][tid + 256];
        const float mx = fmaxf(L0, fmaxf(L1, L2));
        const float e0 = expf(L0 - mx), e1 = expf(L1 - mx), e2 = expf(L2 - mx);
        const float einv = 1.f / (e0 + e1 + e2);
        const float w0 = e0 * einv, w1 = e1 * einv, w2 = e2 * einv;
        // per-thread read-then-overwrite of lgp[s][tid] only: no cross-thread hazard
        lgp[0][tid] = w0; lgp[1][tid] = w1; lgp[2][tid] = w2;
        float* wb = wO + (size_t)b * 3 * HW + rowoff;
        wb[0]      = w0;
        wb[HW]     = w1;
        wb[2 * HW] = w2;
    }
    __syncthreads();

    const float w0 = lgp[0][px], w1 = lgp[1][px], w2 = lgp[2][px];
    #pragma unroll 5
    for (int i = 0; i < 25; ++i){
        const int dd = dd0 + i;
        if (dd < 49){
            int s2i = px + 24 - dd;
            s2i = s2i < 0 ? 0 : (s2i > 255 ? 255 : s2i);
            const float icv = Gp[-dd] * sc1 * s2[s2i];
            fnb[(size_t)dd * HW] = icv + w0 * c0p[(size_t)dd * HW]
                                       + w1 * c1p[(size_t)dd * HW]
                                       + w2 * c2p[(size_t)dd * HW];
        }
    }
}

// ---------------------------------------------------------------------------
extern "C" void kernel_launch(void* const* d_in, const int* in_sizes, int n_in,
                              void* d_out, int out_size, void* d_ws, size_t ws_size,
                              hipStream_t stream)
{
    const float* feat_l1 = (const float*)d_in[0];
    const float* feat_r1 = (const float*)d_in[1];
    const float* cv0     = (const float*)d_in[2];
    const float* cv1     = (const float*)d_in[3];
    const float* cv2     = (const float*)d_in[4];
    const float* W_f1    = (const float*)d_in[5];
    const float* b_f1    = (const float*)d_in[6];
    const float* W_f2    = (const float*)d_in[7];
    const float* b_f2    = (const float*)d_in[8];
    const float* W_geo   = (const float*)d_in[9];
    const float* b_geo   = (const float*)d_in[10];
    const float* W_sel   = (const float*)d_in[11];
    const float* b_sel   = (const float*)d_in[12];

    float* finalO = (float*)d_out;
    float* icO    = (float*)d_out + 6422528;    // 4*49*128*256
    float* wO     = (float*)d_out + 12845056;   // + another 6422528

    unsigned int* Wb = (unsigned int*)d_ws;     // 16384 uints = 64 KB
    float* Mbuf  = (float*)((char*)d_ws + 65536);
    float* c0buf = Mbuf + 441;

    k_pre<<<65, 256, 0, stream>>>(W_f1, W_f2, Wb, W_sel, b_sel, W_geo, b_geo, Mbuf, c0buf);
    k_fused<<<512, 512, 0, stream>>>(feat_l1, feat_r1, Wb, b_f1, b_f2,
                                     cv0, cv1, cv2, Mbuf, c0buf,
                                     icO, finalO, wO);
}

// Round 7
// 284.272 us; speedup vs baseline: 1.0053x; 1.0053x over previous
//
#include <hip/hip_runtime.h>

#define HW 32768      // H*W per batch = 128*256
#define WIDTH 256

typedef float f32x4 __attribute__((ext_vector_type(4)));
typedef short s16x8 __attribute__((ext_vector_type(8)));

__device__ __forceinline__ unsigned short f2bf(float f){
    unsigned int u = __float_as_uint(f);
    u += 0x7FFFu + ((u >> 16) & 1u);      // round-to-nearest-even
    return (unsigned short)(u >> 16);
}
__device__ __forceinline__ unsigned int pk2(float a, float b){
    return (unsigned int)f2bf(a) | ((unsigned int)f2bf(b) << 16);
}

// ---------------------------------------------------------------------------
// k_pre: blocks 0..63 = W1/W2 pre-pack into bf16 MFMA A-fragment layout
//        block 64 = collapsed geo path (M = Wsel x Wgeo, c0 = collapsed bias)
// ---------------------------------------------------------------------------
__global__ void k_pre(const float* __restrict__ W1, const float* __restrict__ W2,
                      unsigned int* __restrict__ Wb,
                      const float* __restrict__ Wsel, const float* __restrict__ bsel,
                      const float* __restrict__ Wgeo, const float* __restrict__ bgeo,
                      float* __restrict__ M, float* __restrict__ c0)
{
    if (blockIdx.x < 64){
        const int pi = blockIdx.x * 256 + threadIdx.x;   // 0..16383
        const int j2   = pi & 3;
        const int l15  = (pi >> 2) & 15;
        const int quad = (pi >> 6) & 3;
        const int m    = (pi >> 8) & 7;
        const int kk   = (pi >> 11) & 3;
        const int F    = (pi >> 13) & 1;
        const float* Wm = F ? W2 : W1;
        const int row = m * 16 + l15;
        const int ch  = kk * 32 + quad * 8 + j2 * 2;
        Wb[pi] = pk2(Wm[row * 128 + ch], Wm[row * 128 + ch + 1]);
    } else {
        for (int u = threadIdx.x; u < 444; u += 256){
            if (u < 441){
                int s = u / 147; int r = u % 147; int i = r / 49; int k = r % 49;
                float acc = 0.f;
                for (int o = 0; o < 96; ++o)
                    acc += Wsel[s * 288 + i * 96 + o] * Wgeo[o * 49 + k];
                M[u] = acc;
            } else {
                int s = u - 441;
                float acc = bsel[s];
                for (int i = 0; i < 3; ++i)
                    for (int o = 0; o < 96; ++o)
                        acc += Wsel[s * 288 + i * 96 + o] * bgeo[o];
                c0[s] = acc;
            }
        }
    }
}

// ---------------------------------------------------------------------------
// Fused kernel, 256 threads (4 waves), one (b,h) row per block (R1 core).
// Request-width upgrades this round:
//  - feat load pipeline 3-deep (24 outstanding scalar loads/wave)
//  - f2s stride 144 shorts (288B = 8 words mod 32): corr B-frag is ONE
//    aligned ds_read_b128 with uniform bank distribution
//  - epilogue: thread = (4-px group, 13-dd slice); all cv loads and all
//    ic/final/w stores are float4 (16B/lane, 1KB/wave-instr); logit partials
//    combined across slices with two __shfl_xor (same wave, no LDS).
// ---------------------------------------------------------------------------
__global__ __launch_bounds__(256, 2) void k_fused(
    const float* __restrict__ fl, const float* __restrict__ fr,
    const unsigned int* __restrict__ Wbu,
    const float* __restrict__ b1, const float* __restrict__ b2,
    const float* __restrict__ cv0, const float* __restrict__ cv1,
    const float* __restrict__ cv2,
    const float* __restrict__ Mg, const float* __restrict__ c0g,
    float* __restrict__ icO, float* __restrict__ finalO, float* __restrict__ wO)
{
    __shared__ __align__(16) char pool[73728];      // f2s[256][144] bf16 -> G[256][66] f32
    __shared__ float s1[256], s2[256];
    __shared__ float Ms[441];
    __shared__ float c0s[3];
    unsigned short* f2s = (unsigned short*)pool;    // [256 px][144] bf16
    float* G            = (float*)pool;             // [256 rows][66] f32

    const int blk  = blockIdx.x;          // 512 = 4 b x 128 h
    const int b    = blk >> 7;
    const int h    = blk & 127;
    const int tid  = threadIdx.x;
    const int wv   = tid >> 6;            // 0..3
    const int lane = tid & 63;
    const int quad = lane >> 4;
    const int l15  = lane & 15;

    for (int i = tid; i < 441; i += 256) Ms[i] = Mg[i];
    if (tid < 3) c0s[tid] = c0g[tid];

    const float* feats[2] = { fl + (size_t)b * 128 * HW + h * WIDTH,
                              fr + (size_t)b * 128 * HW + h * WIDTH };
    const float* bss[2]   = { b1, b2 };

    unsigned int f1p[64];                 // f1 raw bf16 pairs (wave's 64 px)

    #pragma unroll 1
    for (int Fi = 0; Fi < 2; ++Fi){
        const int F = 1 - Fi;             // f2 first, then f1
        const float* featB = feats[F];
        const float* bias  = bss[F];
        const unsigned int* WbF = Wbu + F * 8192;

        f32x4 acc[8][4];
        #pragma unroll
        for (int m = 0; m < 8; ++m)
            #pragma unroll
            for (int nt = 0; nt < 4; ++nt)
                acc[m][nt] = (f32x4){0.f, 0.f, 0.f, 0.f};

        float buf[4][8];
        // tile t = kk*4+nt ; px = wv*64 + nt*16 + l15 ; preload t = 0,1,2
        #pragma unroll
        for (int t = 0; t < 3; ++t){
            const float* bp = featB + (size_t)(quad * 8) * HW + wv * 64 + t * 16 + l15;
            #pragma unroll
            for (int j = 0; j < 8; ++j) buf[t][j] = bp[(size_t)j * HW];
        }

        #pragma unroll
        for (int kk = 0; kk < 4; ++kk){
            // A-frags: one 16-B coalesced load per m (pre-packed bf16, L2-hot)
            s16x8 af[8];
            #pragma unroll
            for (int m = 0; m < 8; ++m)
                af[m] = *(const s16x8*)&WbF[(((kk * 8 + m) * 4 + quad) * 16 + l15) * 4];

            #pragma unroll
            for (int nt = 0; nt < 4; ++nt){
                const int t = kk * 4 + nt;
                if (t + 3 < 16){          // 3-deep pipeline
                    const int kk2 = (t + 3) >> 2, nt2 = (t + 3) & 3;
                    const float* bp = featB + (size_t)(kk2 * 32 + quad * 8) * HW
                                      + wv * 64 + nt2 * 16 + l15;
                    #pragma unroll
                    for (int j = 0; j < 8; ++j) buf[(t + 3) & 3][j] = bp[(size_t)j * HW];
                }
                const float* cur = buf[t & 3];
                union { unsigned int u[4]; s16x8 v; } rb;
                rb.u[0] = pk2(cur[0], cur[1]); rb.u[1] = pk2(cur[2], cur[3]);
                rb.u[2] = pk2(cur[4], cur[5]); rb.u[3] = pk2(cur[6], cur[7]);
                #pragma unroll
                for (int m = 0; m < 8; ++m)
                    acc[m][nt] = __builtin_amdgcn_mfma_f32_16x16x32_bf16(af[m], rb.v, acc[m][nt], 0, 0, 0);
            }
        }

        // bias + inverse-norm per pixel
        float inv[4];
        #pragma unroll
        for (int nt = 0; nt < 4; ++nt){
            #pragma unroll
            for (int m = 0; m < 8; ++m)
                acc[m][nt] += *(const f32x4*)(bias + m * 16 + quad * 4);
            float n2 = 0.f;
            #pragma unroll
            for (int m = 0; m < 8; ++m)
                #pragma unroll
                for (int r = 0; r < 4; ++r)
                    n2 += acc[m][nt][r] * acc[m][nt][r];
            n2 += __shfl_xor(n2, 16, 64);
            n2 += __shfl_xor(n2, 32, 64);
            inv[nt] = 1.f / (sqrtf(n2) + 1e-8f);
        }

        if (F == 1){                      // f2 -> LDS (raw bf16) + s2
            if (quad == 0){
                #pragma unroll
                for (int nt = 0; nt < 4; ++nt) s2[wv * 64 + nt * 16 + l15] = inv[nt];
            }
            #pragma unroll
            for (int nt = 0; nt < 4; ++nt){
                const int px = wv * 64 + nt * 16 + l15;
                #pragma unroll
                for (int m = 0; m < 8; ++m){
                    uint2 p;
                    p.x = pk2(acc[m][nt][0], acc[m][nt][1]);
                    p.y = pk2(acc[m][nt][2], acc[m][nt][3]);
                    *(uint2*)&f2s[px * 144 + m * 16 + quad * 4] = p;
                }
            }
        } else {                          // f1 -> registers (raw bf16) + s1
            #pragma unroll
            for (int m = 0; m < 8; ++m)
                #pragma unroll
                for (int nt = 0; nt < 4; ++nt){
                    f1p[m * 8 + nt * 2 + 0] = pk2(acc[m][nt][0], acc[m][nt][1]);
                    f1p[m * 8 + nt * 2 + 1] = pk2(acc[m][nt][2], acc[m][nt][3]);
                }
            if (quad == 0){
                #pragma unroll
                for (int nt = 0; nt < 4; ++nt) s1[wv * 64 + nt * 16 + l15] = inv[nt];
            }
        }
    }
    __syncthreads();                      // f2s complete

    // ---- correlation: per wave 4 strips of 16 px; A from f1p shuffles ----
    f32x4 acc_c[4][4];
    #pragma unroll
    for (int st = 0; st < 4; ++st)
        #pragma unroll
        for (int ct = 0; ct < 4; ++ct)
            acc_c[st][ct] = (f32x4){0.f, 0.f, 0.f, 0.f};

    #pragma unroll
    for (int st = 0; st < 4; ++st){
        s16x8 afc[4];
        #pragma unroll
        for (int kk = 0; kk < 4; ++kk){
            union { unsigned int u[4]; s16x8 v; } r;
            #pragma unroll
            for (int j2 = 0; j2 < 4; ++j2){
                const int rp  = j2 & 1;
                const int qs  = (quad & 1) * 2 + (j2 >> 1);
                const int src = qs * 16 + l15;
                unsigned int a0 = (unsigned int)__shfl((int)f1p[(kk * 2 + 0) * 8 + st * 2 + rp], src, 64);
                unsigned int a1 = (unsigned int)__shfl((int)f1p[(kk * 2 + 1) * 8 + st * 2 + rp], src, 64);
                r.u[j2] = (quad >> 1) ? a1 : a0;
            }
            afc[kk] = r.v;
        }
        #pragma unroll
        for (int ct = 0; ct < 4; ++ct){
            const int s = wv * 64 + st * 16 + ct * 16 + l15 - 24;
            const bool valid = (s >= 0) && (s < WIDTH);
            const int sc = valid ? s : 0;
            #pragma unroll
            for (int kk = 0; kk < 4; ++kk){
                s16x8 bf = *(const s16x8*)&f2s[sc * 144 + kk * 32 + quad * 8];
                if (!valid) bf = (s16x8){0,0,0,0,0,0,0,0};
                acc_c[st][ct] = __builtin_amdgcn_mfma_f32_16x16x32_bf16(afc[kk], bf, acc_c[st][ct], 0, 0, 0);
            }
        }
    }
    __syncthreads();                      // all f2s reads done; G overwrites pool
    #pragma unroll
    for (int st = 0; st < 4; ++st)
        #pragma unroll
        for (int ct = 0; ct < 4; ++ct)
            #pragma unroll
            for (int r = 0; r < 4; ++r)
                G[((wv * 4 + st) * 16 + quad * 4 + r) * 66 + ct * 16 + l15] = acc_c[st][ct][r];
    __syncthreads();

    // ---- fused epilogue: thread = (px group of 4, dd slice of 13) ----
    // out[dd][px] = G[px][(px&15)+48-dd] * s1[px] * s2[px+24-dd]  (G=0 when OOB)
    const int g   = tid >> 2;             // 0..63 -> px0 = 4g
    const int sl  = tid & 3;              // dd slice: sl*13 .. sl*13+12 (sl 3: 10)
    const int px0 = g * 4;
    const size_t rowoff = (size_t)h * WIDTH + px0;
    const size_t cvbase = (size_t)b * 49 * HW + rowoff;
    float* icb = icO    + cvbase;
    float* fnb = finalO + cvbase;
    const float* c0p = cv0 + cvbase;
    const float* c1p = cv1 + cvbase;
    const float* c2p = cv2 + cvbase;

    // pass 1: logit partials over this thread's dd slice (float4 cv loads)
    f32x4 lg0 = (f32x4){0.f,0.f,0.f,0.f};
    f32x4 lg1 = (f32x4){0.f,0.f,0.f,0.f};
    f32x4 lg2 = (f32x4){0.f,0.f,0.f,0.f};
    #pragma unroll
    for (int i = 0; i < 13; ++i){
        const int dd = sl * 13 + i;
        if (dd < 49){
            const f32x4 a0 = *(const f32x4*)(c0p + (size_t)dd * HW);
            const f32x4 a1 = *(const f32x4*)(c1p + (size_t)dd * HW);
            const f32x4 a2 = *(const f32x4*)(c2p + (size_t)dd * HW);
            const float m00 = Ms[dd],       m01 = Ms[49  + dd], m02 = Ms[98  + dd];
            const float m10 = Ms[147 + dd], m11 = Ms[196 + dd], m12 = Ms[245 + dd];
            const float m20 = Ms[294 + dd], m21 = Ms[343 + dd], m22 = Ms[392 + dd];
            #pragma unroll
            for (int p = 0; p < 4; ++p){
                lg0[p] += m00 * a0[p] + m01 * a1[p] + m02 * a2[p];
                lg1[p] += m10 * a0[p] + m11 * a1[p] + m12 * a2[p];
                lg2[p] += m20 * a0[p] + m21 * a1[p] + m22 * a2[p];
            }
        }
    }
    // reduce across the 4 slices (lanes tid^1, tid^2: same wave)
    #pragma unroll
    for (int p = 0; p < 4; ++p){
        lg0[p] += __shfl_xor(lg0[p], 1, 64); lg0[p] += __shfl_xor(lg0[p], 2, 64);
        lg1[p] += __shfl_xor(lg1[p], 1, 64); lg1[p] += __shfl_xor(lg1[p], 2, 64);
        lg2[p] += __shfl_xor(lg2[p], 1, 64); lg2[p] += __shfl_xor(lg2[p], 2, 64);
    }

    // softmax per pixel (each thread: its 4 px; redundant across slices)
    f32x4 w0v, w1v, w2v;
    #pragma unroll
    for (int p = 0; p < 4; ++p){
        const float L0 = c0s[0] + lg0[p];
        const float L1 = c0s[1] + lg1[p];
        const float L2 = c0s[2] + lg2[p];
        const float mx = fmaxf(L0, fmaxf(L1, L2));
        const float e0 = expf(L0 - mx), e1 = expf(L1 - mx), e2 = expf(L2 - mx);
        const float einv = 1.f / (e0 + e1 + e2);
        w0v[p] = e0 * einv; w1v[p] = e1 * einv; w2v[p] = e2 * einv;
    }
    if (sl == 0){
        float* wb = wO + (size_t)b * 3 * HW + rowoff;
        *(f32x4*)(wb)          = w0v;
        *(f32x4*)(wb + HW)     = w1v;
        *(f32x4*)(wb + 2 * HW) = w2v;
    }

    const f32x4 s1v = *(const f32x4*)&s1[px0];

    // pass 2: re-read cv (L2/L3-hot), icv from LDS G, write ic + final (float4)
    #pragma unroll
    for (int i = 0; i < 13; ++i){
        const int dd = sl * 13 + i;
        if (dd < 49){
            const f32x4 a0 = *(const f32x4*)(c0p + (size_t)dd * HW);
            const f32x4 a1 = *(const f32x4*)(c1p + (size_t)dd * HW);
            const f32x4 a2 = *(const f32x4*)(c2p + (size_t)dd * HW);
            f32x4 icv, fv;
            #pragma unroll
            for (int p = 0; p < 4; ++p){
                const int px = px0 + p;
                int s2i = px + 24 - dd;
                s2i = s2i < 0 ? 0 : (s2i > 255 ? 255 : s2i);   // OOB -> G entry is 0 anyway
                icv[p] = G[px * 66 + (px & 15) + 48 - dd] * s1v[p] * s2[s2i];
                fv[p]  = icv[p] + w0v[p] * a0[p] + w1v[p] * a1[p] + w2v[p] * a2[p];
            }
            *(f32x4*)(icb + (size_t)dd * HW) = icv;
            *(f32x4*)(fnb + (size_t)dd * HW) = fv;
        }
    }
}

// ---------------------------------------------------------------------------
extern "C" void kernel_launch(void* const* d_in, const int* in_sizes, int n_in,
                              void* d_out, int out_size, void* d_ws, size_t ws_size,
                              hipStream_t stream)
{
    const float* feat_l1 = (const float*)d_in[0];
    const float* feat_r1 = (const float*)d_in[1];
    const float* cv0     = (const float*)d_in[2];
    const float* cv1     = (const float*)d_in[3];
    const float* cv2     = (const float*)d_in[4];
    const float* W_f1    = (const float*)d_in[5];
    const float* b_f1    = (const float*)d_in[6];
    const float* W_f2    = (const float*)d_in[7];
    const float* b_f2    = (const float*)d_in[8];
    const float* W_geo   = (const float*)d_in[9];
    const float* b_geo   = (const float*)d_in[10];
    const float* W_sel   = (const float*)d_in[11];
    const float* b_sel   = (const float*)d_in[12];

    float* finalO = (float*)d_out;
    float* icO    = (float*)d_out + 6422528;    // 4*49*128*256
    float* wO     = (float*)d_out + 12845056;   // + another 6422528

    unsigned int* Wb = (unsigned int*)d_ws;     // 16384 uints = 64 KB
    float* Mbuf  = (float*)((char*)d_ws + 65536);
    float* c0buf = Mbuf + 441;

    k_pre<<<65, 256, 0, stream>>>(W_f1, W_f2, Wb, W_sel, b_sel, W_geo, b_geo, Mbuf, c0buf);
    k_fused<<<512, 256, 0, stream>>>(feat_l1, feat_r1, Wb, b_f1, b_f2,
                                     cv0, cv1, cv2, Mbuf, c0buf,
                                     icO, finalO, wO);
}